// Round 9
// baseline (251.695 us; speedup 1.0000x reference)
//
#include <hip/hip_runtime.h>

// Problem constants: B=2, L=8192, D=1024, f32 in/out.
#define BB 2
#define LL 8192
#define DD 1024
#define NC 128   // time chunks
#define TT 64    // chunk length (2^6)
#define NCOL (DD / 256)              // 4 d-slices
#define FOLD_BATCH 8

// ph = exp(-(pr^2+pi^2)) * exp(i*atan2(pi,pr))
__device__ __forceinline__ void compute_ph(float pr, float pi, float& phr, float& phi) {
    float r2 = fmaf(pr, pr, pi * pi);
    float mag = expf(-r2);
    float r = sqrtf(r2);
    if (r > 1e-30f) {
        float inv = mag / r;
        phr = pr * inv;
        phi = pi * inv;
    } else {
        phr = mag;  // atan2(0,0)=0 -> phase 1+0i
        phi = 0.0f;
    }
}

// Single-kernel decoupled-lookback scan:
//   phase 1: x chunk -> VGPRs; zero-init partial; publish (fence + flag)
//   wait:    thread u polls flag[u] for u < j (parallel, no serial chain)
//   phase 2: fold predecessors' partials (batched loads)
//   phase 3: replay chunk from register-held x; write out
// Co-residency: __launch_bounds__(256,4) caps VGPR at 128 -> 4 blocks/CU ->
// all 1024 blocks resident -> no deadlock regardless of dispatch order.
__global__ __launch_bounds__(256, 4) void k_fused(
    const float* __restrict__ x,
    const float* __restrict__ pr, const float* __restrict__ pi,
    const float* __restrict__ qr, const float* __restrict__ qi,
    const float* __restrict__ lr, const float* __restrict__ li,
    float2* __restrict__ partial,
    unsigned int* __restrict__ flags,   // [BB*NCOL][NC]
    float* __restrict__ out)
{
    const int tid = threadIdx.x;
    const int d   = blockIdx.x * 256 + tid;
    const int j   = blockIdx.y;
    const int b   = blockIdx.z;
    unsigned int* colflags = flags + ((size_t)b * NCOL + blockIdx.x) * NC;

    float phr, phi; compute_ph(pr[d], pi[d], phr, phi);
    const float qre = qr[d], qim = qi[d];

    const size_t base = ((size_t)b * LL + (size_t)j * TT) * DD + d;
    const float* xp = x + base;

    // ---- phase 1: x -> registers; zero-init chunk partial ----
    float xv[TT];
    #pragma unroll
    for (int t = 0; t < TT; ++t) xv[t] = xp[(size_t)t * DD];

    {
        float sr = 0.f, si = 0.f;
        #pragma unroll
        for (int t = 0; t < TT; ++t) {
            float nr = fmaf(phr, sr, fmaf(-phi, si, qre * xv[t]));
            float ni = fmaf(phi, sr, fmaf(phr, si, qim * xv[t]));
            sr = nr; si = ni;
        }
        partial[((size_t)b * NC + j) * DD + d] = make_float2(sr, si);
    }

    // ---- publish: block's partial visible device-wide, then set flag ----
    __syncthreads();                       // drains all threads' stores
    if (tid == 0) {
        __threadfence();                   // release to device scope
        __hip_atomic_store(&colflags[j], 1u, __ATOMIC_RELEASE, __HIP_MEMORY_SCOPE_AGENT);
    }

    // ---- wait: parallel poll of predecessor flags (thread u <-> flag u) ----
    if (tid < j) {
        while (__hip_atomic_load(&colflags[tid], __ATOMIC_ACQUIRE,
                                 __HIP_MEMORY_SCOPE_AGENT) == 0u) {
            __builtin_amdgcn_s_sleep(2);
        }
    }
    __syncthreads();
    __threadfence();                       // acquire side, block-wide

    // ---- phase 2: a = ph^TT (6 squarings); fold partials 0..j-1 ----
    float ar = phr, ai = phi;
    #pragma unroll
    for (int k = 0; k < 6; ++k) {
        float nr = ar * ar - ai * ai;
        float ni = 2.f * ar * ai;
        ar = nr; ai = ni;
    }

    float Sr = lr[d], Si = li[d];
    const float2* pb = partial + (size_t)b * NC * DD + d;
    for (int bs = 0; bs < j; bs += FOLD_BATCH) {
        float2 buf[FOLD_BATCH];
        #pragma unroll
        for (int u = 0; u < FOLD_BATCH; ++u) {
            int k = bs + u;
            int kc = (k < j) ? k : (j - 1);   // clamp: always a valid address
            buf[u] = pb[(size_t)kc * DD];
        }
        #pragma unroll
        for (int u = 0; u < FOLD_BATCH; ++u) {
            int k = bs + u;
            if (k < j) {                       // uniform per block
                float nr = fmaf(ar, Sr, fmaf(-ai, Si, buf[u].x));
                float ni = fmaf(ai, Sr, fmaf(ar, Si, buf[u].y));
                Sr = nr; Si = ni;
            }
        }
    }

    // ---- phase 3: replay from register-held x; write out ----
    float* op = out + base;
    #pragma unroll
    for (int t = 0; t < TT; ++t) {
        float nr = fmaf(phr, Sr, fmaf(-phi, Si, qre * xv[t]));
        float ni = fmaf(phi, Sr, fmaf(phr, Si, qim * xv[t]));
        Sr = nr; Si = ni;
        op[(size_t)t * DD] = nr;
    }
}

extern "C" void kernel_launch(void* const* d_in, const int* in_sizes, int n_in,
                              void* d_out, int out_size, void* d_ws, size_t ws_size,
                              hipStream_t stream) {
    const float* x  = (const float*)d_in[0];
    const float* pr = (const float*)d_in[1];
    const float* pi = (const float*)d_in[2];
    const float* qr = (const float*)d_in[3];
    const float* qi = (const float*)d_in[4];
    const float* lr = (const float*)d_in[5];
    const float* li = (const float*)d_in[6];
    float* out = (float*)d_out;

    unsigned int* flags = (unsigned int*)d_ws;               // 8*128*4 = 4 KB
    float2* partial = (float2*)((char*)d_ws + 8192);         // 2 MB

    // reset flags every call (graph-capture-safe async memset)
    hipMemsetAsync(d_ws, 0, 8192, stream);

    dim3 grid(NCOL, NC, BB);   // 4 x 128 x 2 = 1024 blocks
    k_fused<<<grid, 256, 0, stream>>>(x, pr, pi, qr, qi, lr, li, partial, flags, out);
}

// Round 10
// 43.934 us; speedup vs baseline: 5.7289x; 5.7289x over previous
//
#include <hip/hip_runtime.h>

// Problem constants: B=2, L=8192, D=1024, f32 in/out.
#define BB 2
#define LL 8192
#define DD 1024
#define NC 128        // time chunks
#define TT 64         // chunk length (2^6)
#define NPAIR (DD/2)  // 512 d-pairs; one thread <-> one d-pair (8 B/lane)
#define FOLD_BATCH 16

// ph = exp(-(pr^2+pi^2)) * exp(i*atan2(pi,pr))
__device__ __forceinline__ void compute_ph(float pr, float pi, float& phr, float& phi) {
    float r2 = fmaf(pr, pr, pi * pi);
    float mag = expf(-r2);
    float r = sqrtf(r2);
    if (r > 1e-30f) {
        float inv = mag / r;
        phr = pr * inv;
        phi = pi * inv;
    } else {
        phr = mag;  // atan2(0,0)=0 -> phase 1+0i
        phi = 0.0f;
    }
}

// Pass 1: zero-init chunk end-state (read-only stream over x, float2 lanes).
__global__ __launch_bounds__(256) void k_partial(
    const float* __restrict__ x,
    const float* __restrict__ pr, const float* __restrict__ pi,
    const float* __restrict__ qr, const float* __restrict__ qi,
    float4* __restrict__ partial)
{
    const int p = blockIdx.x * 256 + threadIdx.x;   // d-pair 0..511
    const int j = blockIdx.y;
    const int b = blockIdx.z;
    const int d0 = 2 * p, d1 = d0 + 1;

    float phr0, phi0, phr1, phi1;
    compute_ph(pr[d0], pi[d0], phr0, phi0);
    compute_ph(pr[d1], pi[d1], phr1, phi1);
    const float q0r = qr[d0], q0i = qi[d0], q1r = qr[d1], q1i = qi[d1];

    const float2* xp = (const float2*)(x + ((size_t)b * LL + (size_t)j * TT) * DD) + p;

    float sr0 = 0.f, si0 = 0.f, sr1 = 0.f, si1 = 0.f;
    #pragma unroll 16
    for (int t = 0; t < TT; ++t) {
        float2 xv = xp[(size_t)t * NPAIR];
        float nr0 = fmaf(phr0, sr0, fmaf(-phi0, si0, q0r * xv.x));
        float ni0 = fmaf(phi0, sr0, fmaf(phr0, si0, q0i * xv.x));
        float nr1 = fmaf(phr1, sr1, fmaf(-phi1, si1, q1r * xv.y));
        float ni1 = fmaf(phi1, sr1, fmaf(phr1, si1, q1i * xv.y));
        sr0 = nr0; si0 = ni0; sr1 = nr1; si1 = ni1;
    }
    partial[((size_t)b * NC + j) * NPAIR + p] = make_float4(sr0, si0, sr1, si1);
}

// Pass 2: fold partials 0..j-1 (16-deep clamped batches, uniform per block),
// then replay the chunk from the true start state; float2 x-read + out-write.
__global__ __launch_bounds__(256) void k_final(
    const float* __restrict__ x,
    const float* __restrict__ pr, const float* __restrict__ pi,
    const float* __restrict__ qr, const float* __restrict__ qi,
    const float* __restrict__ lr, const float* __restrict__ li,
    const float4* __restrict__ partial,
    float* __restrict__ out)
{
    const int p = blockIdx.x * 256 + threadIdx.x;   // d-pair 0..511
    const int j = blockIdx.y;
    const int b = blockIdx.z;
    const int d0 = 2 * p, d1 = d0 + 1;

    float phr0, phi0, phr1, phi1;
    compute_ph(pr[d0], pi[d0], phr0, phi0);
    compute_ph(pr[d1], pi[d1], phr1, phi1);
    const float q0r = qr[d0], q0i = qi[d0], q1r = qr[d1], q1i = qi[d1];

    // a = ph^TT by repeated squaring (TT = 2^6)
    float a0r = phr0, a0i = phi0, a1r = phr1, a1i = phi1;
    #pragma unroll
    for (int k = 0; k < 6; ++k) {
        float n0r = a0r * a0r - a0i * a0i, n0i = 2.f * a0r * a0i;
        float n1r = a1r * a1r - a1i * a1i, n1i = 2.f * a1r * a1i;
        a0r = n0r; a0i = n0i; a1r = n1r; a1i = n1i;
    }

    // fold: S = last; S <- a*S + P_k for k = 0..j-1 (uniform trip count)
    float S0r = lr[d0], S0i = li[d0], S1r = lr[d1], S1i = li[d1];
    const float4* pb = partial + (size_t)b * NC * NPAIR + p;
    for (int bs = 0; bs < j; bs += FOLD_BATCH) {
        float4 buf[FOLD_BATCH];
        #pragma unroll
        for (int u = 0; u < FOLD_BATCH; ++u) {
            int k = bs + u;
            int kc = (k < j) ? k : (j - 1);   // clamp: always a valid address
            buf[u] = pb[(size_t)kc * NPAIR];
        }
        #pragma unroll
        for (int u = 0; u < FOLD_BATCH; ++u) {
            int k = bs + u;
            if (k < j) {
                float n0r = fmaf(a0r, S0r, fmaf(-a0i, S0i, buf[u].x));
                float n0i = fmaf(a0i, S0r, fmaf(a0r, S0i, buf[u].y));
                float n1r = fmaf(a1r, S1r, fmaf(-a1i, S1i, buf[u].z));
                float n1i = fmaf(a1i, S1r, fmaf(a1r, S1i, buf[u].w));
                S0r = n0r; S0i = n0i; S1r = n1r; S1i = n1i;
            }
        }
    }

    // replay chunk from true start state; emit Re(state)
    const size_t rowbase = (size_t)b * LL + (size_t)j * TT;
    const float2* xp = (const float2*)(x + rowbase * DD) + p;
    float2* op = (float2*)(out + rowbase * DD) + p;
    #pragma unroll 16
    for (int t = 0; t < TT; ++t) {
        float2 xv = xp[(size_t)t * NPAIR];
        float n0r = fmaf(phr0, S0r, fmaf(-phi0, S0i, q0r * xv.x));
        float n0i = fmaf(phi0, S0r, fmaf(phr0, S0i, q0i * xv.x));
        float n1r = fmaf(phr1, S1r, fmaf(-phi1, S1i, q1r * xv.y));
        float n1i = fmaf(phi1, S1r, fmaf(phr1, S1i, q1i * xv.y));
        S0r = n0r; S0i = n0i; S1r = n1r; S1i = n1i;
        op[(size_t)t * NPAIR] = make_float2(n0r, n1r);
    }
}

extern "C" void kernel_launch(void* const* d_in, const int* in_sizes, int n_in,
                              void* d_out, int out_size, void* d_ws, size_t ws_size,
                              hipStream_t stream) {
    const float* x  = (const float*)d_in[0];
    const float* pr = (const float*)d_in[1];
    const float* pi = (const float*)d_in[2];
    const float* qr = (const float*)d_in[3];
    const float* qi = (const float*)d_in[4];
    const float* lr = (const float*)d_in[5];
    const float* li = (const float*)d_in[6];
    float* out = (float*)d_out;

    float4* partial = (float4*)d_ws;   // BB*NC*NPAIR float4 = 2 MB

    dim3 grid(NPAIR / 256, NC, BB);    // 2 x 128 x 2 = 512 blocks
    k_partial<<<grid, 256, 0, stream>>>(x, pr, pi, qr, qi, partial);
    k_final<<<grid, 256, 0, stream>>>(x, pr, pi, qr, qi, lr, li, partial, out);
}